// Round 2
// baseline (424.748 us; speedup 1.0000x reference)
//
#include <hip/hip_runtime.h>
#include <hip/hip_bf16.h>
#include <stdint.h>

typedef _Float16 f16;
typedef _Float16 half8 __attribute__((ext_vector_type(8)));
typedef float floatx4 __attribute__((ext_vector_type(4)));

#define LOG2E 1.44269504088896340736f

__device__ __forceinline__ float bf2f(uint16_t u) {
    union { uint32_t i; float f; } v; v.i = ((uint32_t)u) << 16; return v.f;
}

// dtype sniff: sample 64 even-index uint16s of a weight buffer (|w|<0.089).
// If the buffer is really fp32, even uint16s are low mantissa halves -> random
// bf16 exponents -> some |v|>=1 (or NaN) with overwhelming probability.
__device__ __forceinline__ int sniff_fp32(const void* wq, int tid) {
    const uint16_t* p = (const uint16_t*)wq;
    float v = bf2f(p[(tid & 63) * 2]);
    unsigned long long m = __ballot(!(__builtin_fabsf(v) < 1.0f)); // NaN-safe
    return m != 0ull;
}

__device__ __forceinline__ float ldf(const void* p, size_t i, int fp32) {
    return fp32 ? ((const float*)p)[i] : bf2f(((const uint16_t*)p)[i]);
}

// load 8 consecutive elements (i multiple of 8) as f16x8, either dtype
__device__ __forceinline__ half8 load8(const void* p, size_t i, int fp32) {
    half8 h;
    if (fp32) {
        const float* f = (const float*)p + i;
        float4 a = *(const float4*)f, b = *(const float4*)(f + 4);
        h[0] = (f16)a.x; h[1] = (f16)a.y; h[2] = (f16)a.z; h[3] = (f16)a.w;
        h[4] = (f16)b.x; h[5] = (f16)b.y; h[6] = (f16)b.z; h[7] = (f16)b.w;
    } else {
        const uint16_t* u = (const uint16_t*)p + i;
        uint4 r = *(const uint4*)u;
        h[0] = (f16)bf2f((uint16_t)(r.x & 0xffffu)); h[1] = (f16)bf2f((uint16_t)(r.x >> 16));
        h[2] = (f16)bf2f((uint16_t)(r.y & 0xffffu)); h[3] = (f16)bf2f((uint16_t)(r.y >> 16));
        h[4] = (f16)bf2f((uint16_t)(r.z & 0xffffu)); h[5] = (f16)bf2f((uint16_t)(r.z >> 16));
        h[6] = (f16)bf2f((uint16_t)(r.w & 0xffffu)); h[7] = (f16)bf2f((uint16_t)(r.w >> 16));
    }
    return h;
}

// ---------------------------------------------------------------------------
// K1: QKV projections.  out = W @ x + b per batch.
//   p=0 (q), p=1 (k): write TRANSPOSED  q_t/k_t[b][n][c]  (f16)
//   p=2 (v): write natural v_n[b][c][n] (f16), plus val_t[b][n][c] copy of the
//            (converted) input `value` for the residual in K3.
// grid = 3*B*64 = 384 blocks of 256.
// ---------------------------------------------------------------------------
__global__ __launch_bounds__(256) void k_qkv(
    const void* __restrict__ q_in, const void* __restrict__ k_in,
    const void* __restrict__ v_in,
    const void* __restrict__ wq, const void* __restrict__ bq,
    const void* __restrict__ wk, const void* __restrict__ bk,
    const void* __restrict__ wv, const void* __restrict__ bv,
    f16* __restrict__ q_t, f16* __restrict__ k_t,
    f16* __restrict__ v_n, f16* __restrict__ val_t)
{
    __shared__ f16 w_lds[128 * 136];   // W[c_out][c_in], row pad 136
    __shared__ f16 x_lds[64 * 136];    // x^T[n][c_in]

    int bx  = blockIdx.x;
    int p   = bx >> 7;              // 0..2
    int rem = bx & 127;
    int b   = rem >> 6;
    int n0  = (rem & 63) * 64;

    const void* X  = (p == 0) ? q_in : (p == 1) ? k_in : v_in;
    const void* W  = (p == 0) ? wq   : (p == 1) ? wk   : wv;
    const void* BI = (p == 0) ? bq   : (p == 1) ? bk   : bv;

    int tid = threadIdx.x;
    int fp32 = sniff_fp32(wq, tid);

    // stage W (128x128 -> f16), 2048 chunks of 8
    for (int id = tid; id < 2048; id += 256) {
        int row = id >> 4, c8 = id & 15;
        *(half8*)(w_lds + row * 136 + c8 * 8) = load8(W, (size_t)row * 128 + c8 * 8, fp32);
    }
    // stage X^T (scalar transpose, one-time)
    {
        int n = tid & 63, cg = tid >> 6;
        size_t base = (size_t)b * 128 * 4096 + n0 + n;
        for (int k = 0; k < 32; ++k) {
            int c = cg * 32 + k;
            x_lds[n * 136 + c] = (f16)ldf(X, base + (size_t)c * 4096, fp32);
        }
    }
    __syncthreads();

    if (p == 2) {
        // persist transposed (f16) copy of `value` for K3's residual
        for (int id = tid; id < 1024; id += 256) {
            int row = id >> 4, c8 = id & 15;
            *(uint4*)(val_t + ((size_t)b * 4096 + n0 + row) * 128 + c8 * 8) =
                *(const uint4*)(x_lds + row * 136 + c8 * 8);
        }
    }

    int lane = tid & 63, w = tid >> 6;
    int l16 = lane & 15, quad = lane >> 4;

    if (p < 2) {
        // out_t[n][c_out]: A = x^T strip (m=n), B = W rows (n=c_out)
        floatx4 acc[8] = {};
        for (int kc = 0; kc < 4; ++kc) {
            half8 a = *(half8*)(x_lds + (w * 16 + l16) * 136 + kc * 32 + quad * 8);
#pragma unroll
            for (int f = 0; f < 8; ++f) {
                half8 bf = *(half8*)(w_lds + (f * 16 + l16) * 136 + kc * 32 + quad * 8);
                acc[f] = __builtin_amdgcn_mfma_f32_16x16x32_f16(a, bf, acc[f], 0, 0, 0);
            }
        }
        f16* OUT = (p == 0) ? q_t : k_t;
#pragma unroll
        for (int f = 0; f < 8; ++f) {
            int c = f * 16 + l16;
            float bias = ldf(BI, c, fp32);
#pragma unroll
            for (int rg = 0; rg < 4; ++rg) {
                int n = n0 + w * 16 + quad * 4 + rg;
                OUT[((size_t)b * 4096 + n) * 128 + c] = (f16)(acc[f][rg] + bias);
            }
        }
    } else {
        // natural out[c_out][n]: A = W rows (m=c_out), B = x^T (n=spatial)
        floatx4 acc[2][4] = {};
        int cbase = w * 32;
        for (int kc = 0; kc < 4; ++kc) {
            half8 a0 = *(half8*)(w_lds + (cbase + l16) * 136 + kc * 32 + quad * 8);
            half8 a1 = *(half8*)(w_lds + (cbase + 16 + l16) * 136 + kc * 32 + quad * 8);
#pragma unroll
            for (int nc = 0; nc < 4; ++nc) {
                half8 bf = *(half8*)(x_lds + (nc * 16 + l16) * 136 + kc * 32 + quad * 8);
                acc[0][nc] = __builtin_amdgcn_mfma_f32_16x16x32_f16(a0, bf, acc[0][nc], 0, 0, 0);
                acc[1][nc] = __builtin_amdgcn_mfma_f32_16x16x32_f16(a1, bf, acc[1][nc], 0, 0, 0);
            }
        }
#pragma unroll
        for (int mi = 0; mi < 2; ++mi)
#pragma unroll
            for (int rg = 0; rg < 4; ++rg) {
                int c = cbase + mi * 16 + quad * 4 + rg;
                float bias = ldf(BI, c, fp32);
#pragma unroll
                for (int nc = 0; nc < 4; ++nc) {
                    int n = n0 + nc * 16 + l16;
                    v_n[((size_t)b * 128 + c) * 4096 + n] = (f16)(acc[mi][nc][rg] + bias);
                }
            }
    }
}

// ---------------------------------------------------------------------------
// K2: flash attention.  grid = B*128 = 256 blocks of 256 (4 waves).
// Block covers 32 query rows; waves = 2 row-strips x 2 j-halves.
// ---------------------------------------------------------------------------
union AttnSmemU {
    struct { f16 kT[64 * 136]; f16 v[128 * 72]; } s;
    struct { float o[2][16 * 132]; float m[2][16]; float l[2][16]; } mg;
};

__global__ __launch_bounds__(256) void k_attn(
    const f16* __restrict__ q_t, const f16* __restrict__ k_t,
    const f16* __restrict__ v_n, f16* __restrict__ h_t)
{
    __shared__ f16 q_s[32 * 136];
    __shared__ AttnSmemU u;
    __shared__ f16 p_s[4][16 * 40];

    int bx = blockIdx.x;
    int b = bx >> 7;
    int i_blk = (bx & 127) * 32;
    int tid = threadIdx.x, lane = tid & 63, w = tid >> 6;
    int l16 = lane & 15, quad = lane >> 4;
    int r = w & 1, jh = w >> 1;
    int jj0 = jh * 32;

    // stage Q strip (32x128)
    for (int id = tid; id < 512; id += 256) {
        int row = id >> 4, c8 = id & 15;
        *(uint4*)(q_s + row * 136 + c8 * 8) =
            *(const uint4*)(q_t + ((size_t)b * 4096 + i_blk + row) * 128 + c8 * 8);
    }

    float m_r[4], l_r[4];
    floatx4 acc[8] = {};
#pragma unroll
    for (int i = 0; i < 4; ++i) { m_r[i] = -1e30f; l_r[i] = 0.f; }

    for (int jt = 0; jt < 64; ++jt) {
        __syncthreads();
        // stage K^T tile: 64 rows (j) x 128 (c), direct copy from k_t[b][j][c]
        for (int id = tid; id < 1024; id += 256) {
            int row = id >> 4, c8 = id & 15;
            *(uint4*)(u.s.kT + row * 136 + c8 * 8) =
                *(const uint4*)(k_t + ((size_t)b * 4096 + jt * 64 + row) * 128 + c8 * 8);
        }
        // stage V tile: 128 rows (c) x 64 (j), direct copy from v_n[b][c][j]
        for (int id = tid; id < 1024; id += 256) {
            int c = id >> 3, c8 = id & 7;
            *(uint4*)(u.s.v + c * 72 + c8 * 8) =
                *(const uint4*)(v_n + ((size_t)b * 128 + c) * 4096 + jt * 64 + c8 * 8);
        }
        __syncthreads();

        // S = Q K^T : 16 rows x 32 cols (this wave's j-half)
        floatx4 s0 = {}, s1 = {};
#pragma unroll
        for (int kc = 0; kc < 4; ++kc) {
            half8 a  = *(half8*)(q_s + (r * 16 + l16) * 136 + kc * 32 + quad * 8);
            half8 b0 = *(half8*)(u.s.kT + (jj0 + l16) * 136 + kc * 32 + quad * 8);
            half8 b1 = *(half8*)(u.s.kT + (jj0 + 16 + l16) * 136 + kc * 32 + quad * 8);
            s0 = __builtin_amdgcn_mfma_f32_16x16x32_f16(a, b0, s0, 0, 0, 0);
            s1 = __builtin_amdgcn_mfma_f32_16x16x32_f16(a, b1, s1, 0, 0, 0);
        }

        // online softmax (row = quad*4+rg, 16 lanes per row-group)
        float al[4];
#pragma unroll
        for (int rg = 0; rg < 4; ++rg) {
            float mc = fmaxf(s0[rg], s1[rg]);
            mc = fmaxf(mc, __shfl_xor(mc, 1));
            mc = fmaxf(mc, __shfl_xor(mc, 2));
            mc = fmaxf(mc, __shfl_xor(mc, 4));
            mc = fmaxf(mc, __shfl_xor(mc, 8));
            float mn = fmaxf(m_r[rg], mc);
            float a_ = exp2f((m_r[rg] - mn) * LOG2E);
            float p0 = exp2f((s0[rg] - mn) * LOG2E);
            float p1 = exp2f((s1[rg] - mn) * LOG2E);
            float rs = p0 + p1;
            rs += __shfl_xor(rs, 1);
            rs += __shfl_xor(rs, 2);
            rs += __shfl_xor(rs, 4);
            rs += __shfl_xor(rs, 8);
            l_r[rg] = l_r[rg] * a_ + rs;
            m_r[rg] = mn;
            al[rg] = a_;
            int ro = (quad * 4 + rg) * 40;
            p_s[w][ro + l16] = (f16)p0;
            p_s[w][ro + 16 + l16] = (f16)p1;
        }
#pragma unroll
        for (int f = 0; f < 8; ++f)
#pragma unroll
            for (int rg = 0; rg < 4; ++rg) acc[f][rg] *= al[rg];

        // O += P V^T  (A = P via LDS round-trip, B = V natural)
        half8 ap = *(half8*)(p_s[w] + l16 * 40 + quad * 8);
#pragma unroll
        for (int f = 0; f < 8; ++f) {
            half8 bv = *(half8*)(u.s.v + (f * 16 + l16) * 72 + jj0 + quad * 8);
            acc[f] = __builtin_amdgcn_mfma_f32_16x16x32_f16(ap, bv, acc[f], 0, 0, 0);
        }
    }

    // merge the two j-halves per row-strip
    __syncthreads();
    if (jh == 1) {
#pragma unroll
        for (int f = 0; f < 8; ++f)
#pragma unroll
            for (int rg = 0; rg < 4; ++rg)
                u.mg.o[r][(quad * 4 + rg) * 132 + f * 16 + l16] = acc[f][rg];
        if (l16 == 0)
#pragma unroll
            for (int rg = 0; rg < 4; ++rg) {
                u.mg.m[r][quad * 4 + rg] = m_r[rg];
                u.mg.l[r][quad * 4 + rg] = l_r[rg];
            }
    }
    __syncthreads();
    if (jh == 0) {
        float e0[4], e1[4], inv[4];
#pragma unroll
        for (int rg = 0; rg < 4; ++rg) {
            float m1 = u.mg.m[r][quad * 4 + rg];
            float l1 = u.mg.l[r][quad * 4 + rg];
            float ms = fmaxf(m_r[rg], m1);
            float a0 = exp2f((m_r[rg] - ms) * LOG2E);
            float a1 = exp2f((m1 - ms) * LOG2E);
            e0[rg] = a0; e1[rg] = a1;
            inv[rg] = 1.f / (l_r[rg] * a0 + l1 * a1);
        }
#pragma unroll
        for (int f = 0; f < 8; ++f)
#pragma unroll
            for (int rg = 0; rg < 4; ++rg) {
                float o1 = u.mg.o[r][(quad * 4 + rg) * 132 + f * 16 + l16];
                float val = (acc[f][rg] * e0[rg] + o1 * e1[rg]) * inv[rg];
                int i = i_blk + r * 16 + quad * 4 + rg;
                h_t[((size_t)b * 4096 + i) * 128 + f * 16 + l16] = (f16)val;
            }
    }
}

// ---------------------------------------------------------------------------
// K3: out-projection + residual.  x_t[b][n][c] = Wo@h + bo + value  (fp32)
// grid = B*64 = 128 blocks of 256.
// ---------------------------------------------------------------------------
__global__ __launch_bounds__(256) void k_oproj(
    const f16* __restrict__ h_t, const void* __restrict__ wo,
    const void* __restrict__ bo, const f16* __restrict__ val_t,
    float* __restrict__ x_t)
{
    __shared__ f16 wo_lds[128 * 136];
    __shared__ f16 h_lds[64 * 136];
    int bx = blockIdx.x;
    int b = bx >> 6;
    int n0 = (bx & 63) * 64;
    int tid = threadIdx.x;
    int fp32 = sniff_fp32(wo, tid);

    for (int id = tid; id < 2048; id += 256) {
        int row = id >> 4, c8 = id & 15;
        *(half8*)(wo_lds + row * 136 + c8 * 8) = load8(wo, (size_t)row * 128 + c8 * 8, fp32);
    }
    for (int id = tid; id < 1024; id += 256) {
        int row = id >> 4, c8 = id & 15;
        *(uint4*)(h_lds + row * 136 + c8 * 8) =
            *(const uint4*)(h_t + ((size_t)b * 4096 + n0 + row) * 128 + c8 * 8);
    }
    __syncthreads();

    int lane = tid & 63, w = tid >> 6, l16 = lane & 15, quad = lane >> 4;
    floatx4 acc[8] = {};
    for (int kc = 0; kc < 4; ++kc) {
        half8 a = *(half8*)(h_lds + (w * 16 + l16) * 136 + kc * 32 + quad * 8);
#pragma unroll
        for (int f = 0; f < 8; ++f) {
            half8 bf = *(half8*)(wo_lds + (f * 16 + l16) * 136 + kc * 32 + quad * 8);
            acc[f] = __builtin_amdgcn_mfma_f32_16x16x32_f16(a, bf, acc[f], 0, 0, 0);
        }
    }
#pragma unroll
    for (int f = 0; f < 8; ++f) {
        int c = f * 16 + l16;
        float bias = ldf(bo, c, fp32);
#pragma unroll
        for (int rg = 0; rg < 4; ++rg) {
            int n = n0 + w * 16 + quad * 4 + rg;
            size_t off = ((size_t)b * 4096 + n) * 128 + c;
            x_t[off] = acc[f][rg] + bias + (float)val_t[off];
        }
    }
}

// ---------------------------------------------------------------------------
// K4: group-norm (G=32, 4 ch/group, 16384 elems/group) + swish.
// grid = B*32 = 64 blocks of 256.  Output dtype matches input dtype.
// ---------------------------------------------------------------------------
__global__ __launch_bounds__(256) void k_gn(
    const float* __restrict__ x_t, const void* __restrict__ gamma,
    const void* __restrict__ beta, const void* __restrict__ wq_probe,
    void* __restrict__ out)
{
    __shared__ float red[8];
    int bx = blockIdx.x;
    int b = bx >> 5, g = bx & 31;
    int tid = threadIdx.x;
    int fp32 = sniff_fp32(wq_probe, tid);

    float s = 0.f, ss = 0.f;
    for (int idx = tid; idx < 16384; idx += 256) {
        int n = idx >> 2, cc = idx & 3;
        float x = x_t[((size_t)b * 4096 + n) * 128 + g * 4 + cc];
        s += x; ss += x * x;
    }
#pragma unroll
    for (int m = 1; m < 64; m <<= 1) {
        s += __shfl_xor(s, m);
        ss += __shfl_xor(ss, m);
    }
    int w = tid >> 6;
    if ((tid & 63) == 0) { red[w * 2] = s; red[w * 2 + 1] = ss; }
    __syncthreads();
    float S = red[0] + red[2] + red[4] + red[6];
    float SS = red[1] + red[3] + red[5] + red[7];
    float mu = S * (1.f / 16384.f);
    float inv = rsqrtf(SS * (1.f / 16384.f) - mu * mu + 1e-5f);

    for (int cc = 0; cc < 4; ++cc) {
        int c = g * 4 + cc;
        float ga = ldf(gamma, c, fp32), be = ldf(beta, c, fp32);
        for (int n = tid; n < 4096; n += 256) {
            float x = x_t[((size_t)b * 4096 + n) * 128 + c];
            float y = (x - mu) * inv * ga + be;
            float sig = 1.f / (1.f + exp2f(-y * LOG2E));
            float res = y * sig;
            size_t o = ((size_t)b * 128 + c) * 4096 + n;
            if (fp32) ((float*)out)[o] = res;
            else      ((__hip_bfloat16*)out)[o] = __float2bfloat16(res);
        }
    }
}

// ---------------------------------------------------------------------------
extern "C" void kernel_launch(void* const* d_in, const int* in_sizes, int n_in,
                              void* d_out, int out_size, void* d_ws, size_t ws_size,
                              hipStream_t stream)
{
    const void* q_in  = d_in[0];
    const void* k_in  = d_in[1];
    const void* v_in  = d_in[2];
    const void* wq    = d_in[3];
    const void* bq    = d_in[4];
    const void* wk    = d_in[5];
    const void* bk    = d_in[6];
    const void* wv    = d_in[7];
    const void* bv    = d_in[8];
    const void* wo    = d_in[9];
    const void* bo    = d_in[10];
    const void* gamma = d_in[11];
    const void* beta  = d_in[12];

    char* ws = (char*)d_ws;
    f16*   q_t   = (f16*)(ws);                         // 2 MB  [B][N][C]
    f16*   k_t   = (f16*)(ws + (2u << 20));            // 2 MB  [B][N][C]
    f16*   v_n   = (f16*)(ws + (4u << 20));            // 2 MB  [B][C][N]
    f16*   val_t = (f16*)(ws + (6u << 20));            // 2 MB  [B][N][C]
    f16*   h_t   = (f16*)(ws + (8u << 20));            // 2 MB  [B][N][C]
    float* x_t   = (float*)(ws + (10u << 20));         // 4 MB  [B][N][C] fp32

    k_qkv<<<384, 256, 0, stream>>>(q_in, k_in, v_in, wq, bq, wk, bk, wv, bv,
                                   q_t, k_t, v_n, val_t);
    k_attn<<<256, 256, 0, stream>>>(q_t, k_t, v_n, h_t);
    k_oproj<<<128, 256, 0, stream>>>(h_t, wo, bo, val_t, x_t);
    k_gn<<<64, 256, 0, stream>>>(x_t, gamma, beta, wq, d_out);
}

// Round 3
// 298.085 us; speedup vs baseline: 1.4249x; 1.4249x over previous
//
#include <hip/hip_runtime.h>
#include <hip/hip_bf16.h>
#include <stdint.h>

typedef _Float16 f16;
typedef _Float16 half8 __attribute__((ext_vector_type(8)));
typedef float floatx4 __attribute__((ext_vector_type(4)));

#define LOG2E 1.44269504088896340736f

__device__ __forceinline__ float bf2f(uint16_t u) {
    union { uint32_t i; float f; } v; v.i = ((uint32_t)u) << 16; return v.f;
}

// dtype sniff: sample 64 even-index uint16s of a weight buffer (|w|<0.089).
__device__ __forceinline__ int sniff_fp32(const void* wq, int tid) {
    const uint16_t* p = (const uint16_t*)wq;
    float v = bf2f(p[(tid & 63) * 2]);
    unsigned long long m = __ballot(!(__builtin_fabsf(v) < 1.0f)); // NaN-safe
    return m != 0ull;
}

__device__ __forceinline__ float ldf(const void* p, size_t i, int fp32) {
    return fp32 ? ((const float*)p)[i] : bf2f(((const uint16_t*)p)[i]);
}

__device__ __forceinline__ half8 load8(const void* p, size_t i, int fp32) {
    half8 h;
    if (fp32) {
        const float* f = (const float*)p + i;
        float4 a = *(const float4*)f, b = *(const float4*)(f + 4);
        h[0] = (f16)a.x; h[1] = (f16)a.y; h[2] = (f16)a.z; h[3] = (f16)a.w;
        h[4] = (f16)b.x; h[5] = (f16)b.y; h[6] = (f16)b.z; h[7] = (f16)b.w;
    } else {
        const uint16_t* u = (const uint16_t*)p + i;
        uint4 r = *(const uint4*)u;
        h[0] = (f16)bf2f((uint16_t)(r.x & 0xffffu)); h[1] = (f16)bf2f((uint16_t)(r.x >> 16));
        h[2] = (f16)bf2f((uint16_t)(r.y & 0xffffu)); h[3] = (f16)bf2f((uint16_t)(r.y >> 16));
        h[4] = (f16)bf2f((uint16_t)(r.z & 0xffffu)); h[5] = (f16)bf2f((uint16_t)(r.z >> 16));
        h[6] = (f16)bf2f((uint16_t)(r.w & 0xffffu)); h[7] = (f16)bf2f((uint16_t)(r.w >> 16));
    }
    return h;
}

// ---------------------------------------------------------------------------
// K1: QKV projections (unchanged from round 2 — works).
// ---------------------------------------------------------------------------
__global__ __launch_bounds__(256) void k_qkv(
    const void* __restrict__ q_in, const void* __restrict__ k_in,
    const void* __restrict__ v_in,
    const void* __restrict__ wq, const void* __restrict__ bq,
    const void* __restrict__ wk, const void* __restrict__ bk,
    const void* __restrict__ wv, const void* __restrict__ bv,
    f16* __restrict__ q_t, f16* __restrict__ k_t,
    f16* __restrict__ v_n, f16* __restrict__ val_t)
{
    __shared__ f16 w_lds[128 * 136];
    __shared__ f16 x_lds[64 * 136];

    int bx  = blockIdx.x;
    int p   = bx >> 7;
    int rem = bx & 127;
    int b   = rem >> 6;
    int n0  = (rem & 63) * 64;

    const void* X  = (p == 0) ? q_in : (p == 1) ? k_in : v_in;
    const void* W  = (p == 0) ? wq   : (p == 1) ? wk   : wv;
    const void* BI = (p == 0) ? bq   : (p == 1) ? bk   : bv;

    int tid = threadIdx.x;
    int fp32 = sniff_fp32(wq, tid);

    for (int id = tid; id < 2048; id += 256) {
        int row = id >> 4, c8 = id & 15;
        *(half8*)(w_lds + row * 136 + c8 * 8) = load8(W, (size_t)row * 128 + c8 * 8, fp32);
    }
    {
        int n = tid & 63, cg = tid >> 6;
        size_t base = (size_t)b * 128 * 4096 + n0 + n;
        for (int k = 0; k < 32; ++k) {
            int c = cg * 32 + k;
            x_lds[n * 136 + c] = (f16)ldf(X, base + (size_t)c * 4096, fp32);
        }
    }
    __syncthreads();

    if (p == 2) {
        for (int id = tid; id < 1024; id += 256) {
            int row = id >> 4, c8 = id & 15;
            *(uint4*)(val_t + ((size_t)b * 4096 + n0 + row) * 128 + c8 * 8) =
                *(const uint4*)(x_lds + row * 136 + c8 * 8);
        }
    }

    int lane = tid & 63, w = tid >> 6;
    int l16 = lane & 15, quad = lane >> 4;

    if (p < 2) {
        floatx4 acc[8] = {};
        for (int kc = 0; kc < 4; ++kc) {
            half8 a = *(half8*)(x_lds + (w * 16 + l16) * 136 + kc * 32 + quad * 8);
#pragma unroll
            for (int f = 0; f < 8; ++f) {
                half8 bf = *(half8*)(w_lds + (f * 16 + l16) * 136 + kc * 32 + quad * 8);
                acc[f] = __builtin_amdgcn_mfma_f32_16x16x32_f16(a, bf, acc[f], 0, 0, 0);
            }
        }
        f16* OUT = (p == 0) ? q_t : k_t;
#pragma unroll
        for (int f = 0; f < 8; ++f) {
            int c = f * 16 + l16;
            float bias = ldf(BI, c, fp32);
#pragma unroll
            for (int rg = 0; rg < 4; ++rg) {
                int n = n0 + w * 16 + quad * 4 + rg;
                OUT[((size_t)b * 4096 + n) * 128 + c] = (f16)(acc[f][rg] + bias);
            }
        }
    } else {
        floatx4 acc[2][4] = {};
        int cbase = w * 32;
        for (int kc = 0; kc < 4; ++kc) {
            half8 a0 = *(half8*)(w_lds + (cbase + l16) * 136 + kc * 32 + quad * 8);
            half8 a1 = *(half8*)(w_lds + (cbase + 16 + l16) * 136 + kc * 32 + quad * 8);
#pragma unroll
            for (int nc = 0; nc < 4; ++nc) {
                half8 bf = *(half8*)(x_lds + (nc * 16 + l16) * 136 + kc * 32 + quad * 8);
                acc[0][nc] = __builtin_amdgcn_mfma_f32_16x16x32_f16(a0, bf, acc[0][nc], 0, 0, 0);
                acc[1][nc] = __builtin_amdgcn_mfma_f32_16x16x32_f16(a1, bf, acc[1][nc], 0, 0, 0);
            }
        }
#pragma unroll
        for (int mi = 0; mi < 2; ++mi)
#pragma unroll
            for (int rg = 0; rg < 4; ++rg) {
                int c = cbase + mi * 16 + quad * 4 + rg;
                float bias = ldf(BI, c, fp32);
#pragma unroll
                for (int nc = 0; nc < 4; ++nc) {
                    int n = n0 + nc * 16 + l16;
                    v_n[((size_t)b * 128 + c) * 4096 + n] = (f16)(acc[mi][nc][rg] + bias);
                }
            }
    }
}

// ---------------------------------------------------------------------------
// K2: flash attention with 4-way key split across blocks.
// grid = B*128*4 = 1024 blocks of 256 (4 waves): bx = ((b*128+it)*4+s).
// Block processes i-tile of 32 rows x keys [s*1024, (s+1)*1024) in 16 tiles
// of 64.  Q fragments live in registers (loop-invariant).  LDS = 40960 B
// -> 4 blocks/CU, 16 waves/CU.
// Writes normalized O partial (f16) + per-row (m,l) fp32; k_combine merges.
// ---------------------------------------------------------------------------
union AttnSmemU {
    struct { f16 kT[64 * 136]; f16 v[128 * 72]; } s;       // 35840 B
    struct { float o[2][16 * 132]; float m[2][16]; float l[2][16]; } mg; // 17152 B
};

__global__ __launch_bounds__(256) void k_attn(
    const f16* __restrict__ q_t, const f16* __restrict__ k_t,
    const f16* __restrict__ v_n, f16* __restrict__ part_o,
    float* __restrict__ part_ml)
{
    __shared__ AttnSmemU u;
    __shared__ f16 p_s[4][16 * 40];                        // 5120 B

    int bx = blockIdx.x;
    int b  = bx >> 9;
    int it = (bx >> 2) & 127;
    int sp = bx & 3;
    int i_blk = it * 32;
    int tid = threadIdx.x, lane = tid & 63, w = tid >> 6;
    int l16 = lane & 15, quad = lane >> 4;
    int r = w & 1, jh = w >> 1;
    int jj0 = jh * 32;

    // Q fragments: loop-invariant, from global (b128, once)
    half8 qf[4];
    {
        const f16* qp = q_t + ((size_t)b * 4096 + i_blk + r * 16 + l16) * 128 + quad * 8;
#pragma unroll
        for (int kc = 0; kc < 4; ++kc) qf[kc] = *(const half8*)(qp + kc * 32);
    }

    float m_r[4], l_r[4];
    floatx4 acc[8] = {};
#pragma unroll
    for (int i = 0; i < 4; ++i) { m_r[i] = -1e30f; l_r[i] = 0.f; }

    for (int jt = 0; jt < 16; ++jt) {
        int j0 = sp * 1024 + jt * 64;
        __syncthreads();
        for (int id = tid; id < 1024; id += 256) {
            int row = id >> 4, c8 = id & 15;
            *(uint4*)(u.s.kT + row * 136 + c8 * 8) =
                *(const uint4*)(k_t + ((size_t)b * 4096 + j0 + row) * 128 + c8 * 8);
        }
        for (int id = tid; id < 1024; id += 256) {
            int c = id >> 3, c8 = id & 7;
            *(uint4*)(u.s.v + c * 72 + c8 * 8) =
                *(const uint4*)(v_n + ((size_t)b * 128 + c) * 4096 + j0 + c8 * 8);
        }
        __syncthreads();

        // S = Q K^T : 16 rows x 32 cols (this wave's j-half)
        floatx4 s0 = {}, s1 = {};
#pragma unroll
        for (int kc = 0; kc < 4; ++kc) {
            half8 b0 = *(half8*)(u.s.kT + (jj0 + l16) * 136 + kc * 32 + quad * 8);
            half8 b1 = *(half8*)(u.s.kT + (jj0 + 16 + l16) * 136 + kc * 32 + quad * 8);
            s0 = __builtin_amdgcn_mfma_f32_16x16x32_f16(qf[kc], b0, s0, 0, 0, 0);
            s1 = __builtin_amdgcn_mfma_f32_16x16x32_f16(qf[kc], b1, s1, 0, 0, 0);
        }

        // online softmax
        float al[4];
#pragma unroll
        for (int rg = 0; rg < 4; ++rg) {
            float mc = fmaxf(s0[rg], s1[rg]);
            mc = fmaxf(mc, __shfl_xor(mc, 1));
            mc = fmaxf(mc, __shfl_xor(mc, 2));
            mc = fmaxf(mc, __shfl_xor(mc, 4));
            mc = fmaxf(mc, __shfl_xor(mc, 8));
            float mn = fmaxf(m_r[rg], mc);
            float a_ = exp2f((m_r[rg] - mn) * LOG2E);
            float p0 = exp2f((s0[rg] - mn) * LOG2E);
            float p1 = exp2f((s1[rg] - mn) * LOG2E);
            float rs = p0 + p1;
            rs += __shfl_xor(rs, 1);
            rs += __shfl_xor(rs, 2);
            rs += __shfl_xor(rs, 4);
            rs += __shfl_xor(rs, 8);
            l_r[rg] = l_r[rg] * a_ + rs;
            m_r[rg] = mn;
            al[rg] = a_;
            int ro = (quad * 4 + rg) * 40;
            p_s[w][ro + l16] = (f16)p0;
            p_s[w][ro + 16 + l16] = (f16)p1;
        }
#pragma unroll
        for (int f = 0; f < 8; ++f)
#pragma unroll
            for (int rg = 0; rg < 4; ++rg) acc[f][rg] *= al[rg];

        // O += P V
        half8 ap = *(half8*)(p_s[w] + l16 * 40 + quad * 8);
#pragma unroll
        for (int f = 0; f < 8; ++f) {
            half8 bv = *(half8*)(u.s.v + (f * 16 + l16) * 72 + jj0 + quad * 8);
            acc[f] = __builtin_amdgcn_mfma_f32_16x16x32_f16(ap, bv, acc[f], 0, 0, 0);
        }
    }

    // merge the two j-halves per row-strip; write normalized partial + (m,l)
    __syncthreads();
    if (jh == 1) {
#pragma unroll
        for (int f = 0; f < 8; ++f)
#pragma unroll
            for (int rg = 0; rg < 4; ++rg)
                u.mg.o[r][(quad * 4 + rg) * 132 + f * 16 + l16] = acc[f][rg];
        if (l16 == 0)
#pragma unroll
            for (int rg = 0; rg < 4; ++rg) {
                u.mg.m[r][quad * 4 + rg] = m_r[rg];
                u.mg.l[r][quad * 4 + rg] = l_r[rg];
            }
    }
    __syncthreads();
    if (jh == 0) {
        float e0[4], e1[4], inv[4], msv[4], lsv[4];
#pragma unroll
        for (int rg = 0; rg < 4; ++rg) {
            float m1 = u.mg.m[r][quad * 4 + rg];
            float l1 = u.mg.l[r][quad * 4 + rg];
            float ms = fmaxf(m_r[rg], m1);
            float a0 = exp2f((m_r[rg] - ms) * LOG2E);
            float a1 = exp2f((m1 - ms) * LOG2E);
            float ls = l_r[rg] * a0 + l1 * a1;
            e0[rg] = a0; e1[rg] = a1;
            inv[rg] = 1.f / ls;
            msv[rg] = ms; lsv[rg] = ls;
        }
#pragma unroll
        for (int f = 0; f < 8; ++f)
#pragma unroll
            for (int rg = 0; rg < 4; ++rg) {
                float o1 = u.mg.o[r][(quad * 4 + rg) * 132 + f * 16 + l16];
                float val = (acc[f][rg] * e0[rg] + o1 * e1[rg]) * inv[rg];
                int row32 = r * 16 + quad * 4 + rg;
                part_o[(size_t)bx * 4096 + row32 * 128 + f * 16 + l16] = (f16)val;
            }
        if (l16 == 0)
#pragma unroll
            for (int rg = 0; rg < 4; ++rg) {
                int row32 = r * 16 + quad * 4 + rg;
                part_ml[(size_t)bx * 64 + row32]      = msv[rg];
                part_ml[(size_t)bx * 64 + 32 + row32] = lsv[rg];
            }
    }
}

// ---------------------------------------------------------------------------
// K2b: combine 4 key-split partials.  grid = B*128 = 256 blocks of 256.
// O[i] = sum_s w_s O_s[i],  w_s = l_s e^{m_s-M} / sum_s l_s e^{m_s-M}.
// ---------------------------------------------------------------------------
__global__ __launch_bounds__(256) void k_combine(
    const f16* __restrict__ part_o, const float* __restrict__ part_ml,
    f16* __restrict__ h_t)
{
    __shared__ float w4[4][32];
    int bx = blockIdx.x;           // = b*128 + it
    int b = bx >> 7, it = bx & 127;
    int tid = threadIdx.x;
    size_t base4 = (size_t)bx * 4;

    if (tid < 32) {
        float m[4], l[4];
#pragma unroll
        for (int s = 0; s < 4; ++s) {
            m[s] = part_ml[(base4 + s) * 64 + tid];
            l[s] = part_ml[(base4 + s) * 64 + 32 + tid];
        }
        float M = fmaxf(fmaxf(m[0], m[1]), fmaxf(m[2], m[3]));
        float sw = 0.f, w[4];
#pragma unroll
        for (int s = 0; s < 4; ++s) { w[s] = l[s] * exp2f((m[s] - M) * LOG2E); sw += w[s]; }
        float inv = 1.f / sw;
#pragma unroll
        for (int s = 0; s < 4; ++s) w4[s][tid] = w[s] * inv;
    }
    __syncthreads();

    int row = tid >> 3, c16 = (tid & 7) * 16;
    float o[16] = {};
#pragma unroll
    for (int s = 0; s < 4; ++s) {
        const f16* src = part_o + (base4 + s) * 4096 + row * 128 + c16;
        half8 a = *(const half8*)src, c = *(const half8*)(src + 8);
        float w = w4[s][row];
#pragma unroll
        for (int k = 0; k < 8; ++k) { o[k] += w * (float)a[k]; o[8 + k] += w * (float)c[k]; }
    }
    f16* dst = h_t + ((size_t)b * 4096 + it * 32 + row) * 128 + c16;
    half8 r0, r1;
#pragma unroll
    for (int k = 0; k < 8; ++k) { r0[k] = (f16)o[k]; r1[k] = (f16)o[8 + k]; }
    *(half8*)dst = r0;
    *(half8*)(dst + 8) = r1;
}

// ---------------------------------------------------------------------------
// K3: out-projection + residual (unchanged).
// ---------------------------------------------------------------------------
__global__ __launch_bounds__(256) void k_oproj(
    const f16* __restrict__ h_t, const void* __restrict__ wo,
    const void* __restrict__ bo, const f16* __restrict__ val_t,
    float* __restrict__ x_t)
{
    __shared__ f16 wo_lds[128 * 136];
    __shared__ f16 h_lds[64 * 136];
    int bx = blockIdx.x;
    int b = bx >> 6;
    int n0 = (bx & 63) * 64;
    int tid = threadIdx.x;
    int fp32 = sniff_fp32(wo, tid);

    for (int id = tid; id < 2048; id += 256) {
        int row = id >> 4, c8 = id & 15;
        *(half8*)(wo_lds + row * 136 + c8 * 8) = load8(wo, (size_t)row * 128 + c8 * 8, fp32);
    }
    for (int id = tid; id < 1024; id += 256) {
        int row = id >> 4, c8 = id & 15;
        *(uint4*)(h_lds + row * 136 + c8 * 8) =
            *(const uint4*)(h_t + ((size_t)b * 4096 + n0 + row) * 128 + c8 * 8);
    }
    __syncthreads();

    int lane = tid & 63, w = tid >> 6, l16 = lane & 15, quad = lane >> 4;
    floatx4 acc[8] = {};
    for (int kc = 0; kc < 4; ++kc) {
        half8 a = *(half8*)(h_lds + (w * 16 + l16) * 136 + kc * 32 + quad * 8);
#pragma unroll
        for (int f = 0; f < 8; ++f) {
            half8 bf = *(half8*)(wo_lds + (f * 16 + l16) * 136 + kc * 32 + quad * 8);
            acc[f] = __builtin_amdgcn_mfma_f32_16x16x32_f16(a, bf, acc[f], 0, 0, 0);
        }
    }
#pragma unroll
    for (int f = 0; f < 8; ++f) {
        int c = f * 16 + l16;
        float bias = ldf(bo, c, fp32);
#pragma unroll
        for (int rg = 0; rg < 4; ++rg) {
            int n = n0 + w * 16 + quad * 4 + rg;
            size_t off = ((size_t)b * 4096 + n) * 128 + c;
            x_t[off] = acc[f][rg] + bias + (float)val_t[off];
        }
    }
}

// ---------------------------------------------------------------------------
// K4: group-norm + swish (unchanged).
// ---------------------------------------------------------------------------
__global__ __launch_bounds__(256) void k_gn(
    const float* __restrict__ x_t, const void* __restrict__ gamma,
    const void* __restrict__ beta, const void* __restrict__ wq_probe,
    void* __restrict__ out)
{
    __shared__ float red[8];
    int bx = blockIdx.x;
    int b = bx >> 5, g = bx & 31;
    int tid = threadIdx.x;
    int fp32 = sniff_fp32(wq_probe, tid);

    float s = 0.f, ss = 0.f;
    for (int idx = tid; idx < 16384; idx += 256) {
        int n = idx >> 2, cc = idx & 3;
        float x = x_t[((size_t)b * 4096 + n) * 128 + g * 4 + cc];
        s += x; ss += x * x;
    }
#pragma unroll
    for (int m = 1; m < 64; m <<= 1) {
        s += __shfl_xor(s, m);
        ss += __shfl_xor(ss, m);
    }
    int w = tid >> 6;
    if ((tid & 63) == 0) { red[w * 2] = s; red[w * 2 + 1] = ss; }
    __syncthreads();
    float S = red[0] + red[2] + red[4] + red[6];
    float SS = red[1] + red[3] + red[5] + red[7];
    float mu = S * (1.f / 16384.f);
    float inv = rsqrtf(SS * (1.f / 16384.f) - mu * mu + 1e-5f);

    for (int cc = 0; cc < 4; ++cc) {
        int c = g * 4 + cc;
        float ga = ldf(gamma, c, fp32), be = ldf(beta, c, fp32);
        for (int n = tid; n < 4096; n += 256) {
            float x = x_t[((size_t)b * 4096 + n) * 128 + c];
            float y = (x - mu) * inv * ga + be;
            float sig = 1.f / (1.f + exp2f(-y * LOG2E));
            float res = y * sig;
            size_t o = ((size_t)b * 128 + c) * 4096 + n;
            if (fp32) ((float*)out)[o] = res;
            else      ((__hip_bfloat16*)out)[o] = __float2bfloat16(res);
        }
    }
}

// ---------------------------------------------------------------------------
extern "C" void kernel_launch(void* const* d_in, const int* in_sizes, int n_in,
                              void* d_out, int out_size, void* d_ws, size_t ws_size,
                              hipStream_t stream)
{
    const void* q_in  = d_in[0];
    const void* k_in  = d_in[1];
    const void* v_in  = d_in[2];
    const void* wq    = d_in[3];
    const void* bq    = d_in[4];
    const void* wk    = d_in[5];
    const void* bk    = d_in[6];
    const void* wv    = d_in[7];
    const void* bv    = d_in[8];
    const void* wo    = d_in[9];
    const void* bo    = d_in[10];
    const void* gamma = d_in[11];
    const void* beta  = d_in[12];

    char* ws = (char*)d_ws;
    f16*   q_t   = (f16*)(ws);                    // 0..2 MB   [B][N][C]
    f16*   k_t   = (f16*)(ws + (2u << 20));       // 2..4 MB   [B][N][C]
    f16*   v_n   = (f16*)(ws + (4u << 20));       // 4..6 MB   [B][C][N]
    f16*   val_t = (f16*)(ws + (6u << 20));       // 6..8 MB   [B][N][C]
    f16*   h_t   = (f16*)(ws + (8u << 20));       // 8..10 MB  [B][N][C]
    f16*   part_o  = (f16*)(ws + (10u << 20));    // 10..18 MB [1024][32][128]
    float* part_ml = (float*)(ws + (18u << 20));  // 18..18.25 MB
    float* x_t   = (float*)(ws + (10u << 20));    // 10..14 MB (reuses dead part_o)

    k_qkv<<<384, 256, 0, stream>>>(q_in, k_in, v_in, wq, bq, wk, bk, wv, bv,
                                   q_t, k_t, v_n, val_t);
    k_attn<<<1024, 256, 0, stream>>>(q_t, k_t, v_n, part_o, part_ml);
    k_combine<<<256, 256, 0, stream>>>(part_o, part_ml, h_t);
    k_oproj<<<128, 256, 0, stream>>>(h_t, wo, bo, val_t, x_t);
    k_gn<<<64, 256, 0, stream>>>(x_t, gamma, beta, wq, d_out);
}

// Round 4
// 241.160 us; speedup vs baseline: 1.7613x; 1.2360x over previous
//
#include <hip/hip_runtime.h>
#include <hip/hip_bf16.h>
#include <stdint.h>

typedef _Float16 f16;
typedef _Float16 half2v __attribute__((ext_vector_type(2)));
typedef _Float16 half4v __attribute__((ext_vector_type(4)));
typedef _Float16 half8 __attribute__((ext_vector_type(8)));
typedef float floatx4 __attribute__((ext_vector_type(4)));

#define LOG2E 1.44269504088896340736f

__device__ __forceinline__ float bf2f(uint16_t u) {
    union { uint32_t i; float f; } v; v.i = ((uint32_t)u) << 16; return v.f;
}

// dtype sniff: sample 64 even-index uint16s of a weight buffer (|w|<0.089).
__device__ __forceinline__ int sniff_fp32(const void* wq, int tid) {
    const uint16_t* p = (const uint16_t*)wq;
    float v = bf2f(p[(tid & 63) * 2]);
    unsigned long long m = __ballot(!(__builtin_fabsf(v) < 1.0f)); // NaN-safe
    return m != 0ull;
}

__device__ __forceinline__ float ldf(const void* p, size_t i, int fp32) {
    return fp32 ? ((const float*)p)[i] : bf2f(((const uint16_t*)p)[i]);
}

__device__ __forceinline__ half8 load8(const void* p, size_t i, int fp32) {
    half8 h;
    if (fp32) {
        const float* f = (const float*)p + i;
        float4 a = *(const float4*)f, b = *(const float4*)(f + 4);
        h[0] = (f16)a.x; h[1] = (f16)a.y; h[2] = (f16)a.z; h[3] = (f16)a.w;
        h[4] = (f16)b.x; h[5] = (f16)b.y; h[6] = (f16)b.z; h[7] = (f16)b.w;
    } else {
        const uint16_t* u = (const uint16_t*)p + i;
        uint4 r = *(const uint4*)u;
        h[0] = (f16)bf2f((uint16_t)(r.x & 0xffffu)); h[1] = (f16)bf2f((uint16_t)(r.x >> 16));
        h[2] = (f16)bf2f((uint16_t)(r.y & 0xffffu)); h[3] = (f16)bf2f((uint16_t)(r.y >> 16));
        h[4] = (f16)bf2f((uint16_t)(r.z & 0xffffu)); h[5] = (f16)bf2f((uint16_t)(r.z >> 16));
        h[6] = (f16)bf2f((uint16_t)(r.w & 0xffffu)); h[7] = (f16)bf2f((uint16_t)(r.w >> 16));
    }
    return h;
}

// ---------------------------------------------------------------------------
// K1: QKV projections.  Coalesced X staging (global coalesced, LDS scatter).
// grid = 3*B*64 = 384 blocks of 256.
// ---------------------------------------------------------------------------
__global__ __launch_bounds__(256) void k_qkv(
    const void* __restrict__ q_in, const void* __restrict__ k_in,
    const void* __restrict__ v_in,
    const void* __restrict__ wq, const void* __restrict__ bq,
    const void* __restrict__ wk, const void* __restrict__ bk,
    const void* __restrict__ wv, const void* __restrict__ bv,
    f16* __restrict__ q_t, f16* __restrict__ k_t,
    f16* __restrict__ v_n, f16* __restrict__ val_t)
{
    __shared__ f16 w_lds[128 * 136];
    __shared__ f16 x_lds[64 * 136];

    int bx  = blockIdx.x;
    int p   = bx >> 7;
    int rem = bx & 127;
    int b   = rem >> 6;
    int n0  = (rem & 63) * 64;

    const void* X  = (p == 0) ? q_in : (p == 1) ? k_in : v_in;
    const void* W  = (p == 0) ? wq   : (p == 1) ? wk   : wv;
    const void* BI = (p == 0) ? bq   : (p == 1) ? bk   : bv;

    int tid = threadIdx.x;
    int fp32 = sniff_fp32(wq, tid);

    for (int id = tid; id < 2048; id += 256) {
        int row = id >> 4, c8 = id & 15;
        *(half8*)(w_lds + row * 136 + c8 * 8) = load8(W, (size_t)row * 128 + c8 * 8, fp32);
    }
    // X^T staging: coalesced global reads (consecutive lanes -> consecutive n),
    // packed half2 LDS writes.
    for (int id = tid; id < 4096; id += 256) {
        int c2 = id >> 6, n = id & 63;
        int c = c2 * 2;
        size_t base = (size_t)b * 128 * 4096 + (size_t)c * 4096 + n0 + n;
        f16 v0 = (f16)ldf(X, base, fp32);
        f16 v1 = (f16)ldf(X, base + 4096, fp32);
        *(half2v*)(x_lds + n * 136 + c) = (half2v){v0, v1};
    }
    __syncthreads();

    if (p == 2) {
        for (int id = tid; id < 1024; id += 256) {
            int row = id >> 4, c8 = id & 15;
            *(uint4*)(val_t + ((size_t)b * 4096 + n0 + row) * 128 + c8 * 8) =
                *(const uint4*)(x_lds + row * 136 + c8 * 8);
        }
    }

    int lane = tid & 63, w = tid >> 6;
    int l16 = lane & 15, quad = lane >> 4;

    if (p < 2) {
        floatx4 acc[8] = {};
        for (int kc = 0; kc < 4; ++kc) {
            half8 a = *(half8*)(x_lds + (w * 16 + l16) * 136 + kc * 32 + quad * 8);
#pragma unroll
            for (int f = 0; f < 8; ++f) {
                half8 bf = *(half8*)(w_lds + (f * 16 + l16) * 136 + kc * 32 + quad * 8);
                acc[f] = __builtin_amdgcn_mfma_f32_16x16x32_f16(a, bf, acc[f], 0, 0, 0);
            }
        }
        f16* OUT = (p == 0) ? q_t : k_t;
#pragma unroll
        for (int f = 0; f < 8; ++f) {
            int c = f * 16 + l16;
            float bias = ldf(BI, c, fp32);
#pragma unroll
            for (int rg = 0; rg < 4; ++rg) {
                int n = n0 + w * 16 + quad * 4 + rg;
                OUT[((size_t)b * 4096 + n) * 128 + c] = (f16)(acc[f][rg] + bias);
            }
        }
    } else {
        floatx4 acc[2][4] = {};
        int cbase = w * 32;
        for (int kc = 0; kc < 4; ++kc) {
            half8 a0 = *(half8*)(w_lds + (cbase + l16) * 136 + kc * 32 + quad * 8);
            half8 a1 = *(half8*)(w_lds + (cbase + 16 + l16) * 136 + kc * 32 + quad * 8);
#pragma unroll
            for (int nc = 0; nc < 4; ++nc) {
                half8 bf = *(half8*)(x_lds + (nc * 16 + l16) * 136 + kc * 32 + quad * 8);
                acc[0][nc] = __builtin_amdgcn_mfma_f32_16x16x32_f16(a0, bf, acc[0][nc], 0, 0, 0);
                acc[1][nc] = __builtin_amdgcn_mfma_f32_16x16x32_f16(a1, bf, acc[1][nc], 0, 0, 0);
            }
        }
#pragma unroll
        for (int mi = 0; mi < 2; ++mi)
#pragma unroll
            for (int rg = 0; rg < 4; ++rg) {
                int c = cbase + mi * 16 + quad * 4 + rg;
                float bias = ldf(BI, c, fp32);
#pragma unroll
                for (int nc = 0; nc < 4; ++nc) {
                    int n = n0 + nc * 16 + l16;
                    v_n[((size_t)b * 128 + c) * 4096 + n] = (f16)(acc[mi][nc][rg] + bias);
                }
            }
    }
}

// ---------------------------------------------------------------------------
// K2: flash attention, S^T formulation (key dim on registers/quad -> only
// 2 shuffles per iter).  grid = B*128*4 = 1024 blocks of 256 (4 waves).
// Wave (r, jh): 16 queries (r strip) x 32 keys (jh half of 64-key tile).
// acc = O^T (c-major): lane holds O^T[c = f*16+quad*4+rg][query = l16].
// ---------------------------------------------------------------------------
union AttnSmemU {
    struct { f16 kT[64 * 136]; f16 v[128 * 72]; } s;              // 35840 B
    struct { float o[2][128 * 17]; float m[2][16]; float l[2][16]; } mg; // 17664 B
};

__global__ __launch_bounds__(256) void k_attn(
    const f16* __restrict__ q_t, const f16* __restrict__ k_t,
    const f16* __restrict__ v_n, f16* __restrict__ part_o,
    float* __restrict__ part_ml)
{
    __shared__ AttnSmemU u;
    __shared__ f16 p_s[4][16 * 40];                               // 5120 B

    int bx = blockIdx.x;
    int b  = bx >> 9;
    int it = (bx >> 2) & 127;
    int sp = bx & 3;
    int i_blk = it * 32;
    int tid = threadIdx.x, lane = tid & 63, w = tid >> 6;
    int l16 = lane & 15, quad = lane >> 4;
    int r = w & 1, jh = w >> 1;

    // Q B-fragments (loop-invariant): B[k=kc*32+quad*8+j][n=l16] = Q[query][c]
    half8 qf[4];
    {
        const f16* qp = q_t + ((size_t)b * 4096 + i_blk + r * 16 + l16) * 128 + quad * 8;
#pragma unroll
        for (int kc = 0; kc < 4; ++kc) qf[kc] = *(const half8*)(qp + kc * 32);
    }

    float m_q = -1e30f;   // running max for query l16 (uniform over quad)
    float l_lane = 0.f;   // per-lane partial sum (this lane's 8 keys per iter)
    floatx4 acc[8] = {};

    for (int jt = 0; jt < 16; ++jt) {
        int j0 = sp * 1024 + jt * 64;
        __syncthreads();
        for (int id = tid; id < 1024; id += 256) {
            int row = id >> 4, c8 = id & 15;
            *(uint4*)(u.s.kT + row * 136 + c8 * 8) =
                *(const uint4*)(k_t + ((size_t)b * 4096 + j0 + row) * 128 + c8 * 8);
        }
        for (int id = tid; id < 1024; id += 256) {
            int c = id >> 3, c8 = id & 7;
            *(uint4*)(u.s.v + c * 72 + c8 * 8) =
                *(const uint4*)(v_n + ((size_t)b * 128 + c) * 4096 + j0 + c8 * 8);
        }
        __syncthreads();

        // S^T = K Q^T : A = kT rows (m = key), B = qf.  st[kg]: key group kg*16.
        floatx4 st[2] = {};
#pragma unroll
        for (int kc = 0; kc < 4; ++kc) {
            half8 a0 = *(half8*)(u.s.kT + (jh * 32 + l16) * 136 + kc * 32 + quad * 8);
            half8 a1 = *(half8*)(u.s.kT + (jh * 32 + 16 + l16) * 136 + kc * 32 + quad * 8);
            st[0] = __builtin_amdgcn_mfma_f32_16x16x32_f16(a0, qf[kc], st[0], 0, 0, 0);
            st[1] = __builtin_amdgcn_mfma_f32_16x16x32_f16(a1, qf[kc], st[1], 0, 0, 0);
        }
        // lane holds keys local = kg*16 + quad*4 + rg, query = l16

        // max: 7 in-register + 2 shuffles (cross-quad)
        float mc = fmaxf(fmaxf(fmaxf(st[0][0], st[0][1]), fmaxf(st[0][2], st[0][3])),
                         fmaxf(fmaxf(st[1][0], st[1][1]), fmaxf(st[1][2], st[1][3])));
        mc = fmaxf(mc, __shfl_xor(mc, 16));
        mc = fmaxf(mc, __shfl_xor(mc, 32));
        float mn = fmaxf(m_q, mc);
        float a_ = exp2f((m_q - mn) * LOG2E);
        m_q = mn;

        float psum = 0.f;
        f16 pv[8];
#pragma unroll
        for (int kg = 0; kg < 2; ++kg)
#pragma unroll
            for (int rg = 0; rg < 4; ++rg) {
                float pp = exp2f((st[kg][rg] - mn) * LOG2E);
                psum += pp;
                pv[kg * 4 + rg] = (f16)pp;
            }
        l_lane = l_lane * a_ + psum;

#pragma unroll
        for (int f = 0; f < 8; ++f)
#pragma unroll
            for (int rg = 0; rg < 4; ++rg) acc[f][rg] *= a_;

        // P^T -> p_s [query l16][key local 0..31], packed pairs
#pragma unroll
        for (int kg = 0; kg < 2; ++kg) {
            *(half2v*)(p_s[w] + l16 * 40 + kg * 16 + quad * 4)     = (half2v){pv[kg*4+0], pv[kg*4+1]};
            *(half2v*)(p_s[w] + l16 * 40 + kg * 16 + quad * 4 + 2) = (half2v){pv[kg*4+2], pv[kg*4+3]};
        }

        // O^T += V^T P^T : A = v rows (m=c), B = P^T from p_s (b128, conflict-free)
        half8 pf = *(half8*)(p_s[w] + l16 * 40 + quad * 8);
#pragma unroll
        for (int f = 0; f < 8; ++f) {
            half8 av = *(half8*)(u.s.v + (f * 16 + l16) * 72 + jh * 32 + quad * 8);
            acc[f] = __builtin_amdgcn_mfma_f32_16x16x32_f16(av, pf, acc[f], 0, 0, 0);
        }
    }

    // final l per query (sum over quads)
    float l_q = l_lane;
    l_q += __shfl_xor(l_q, 16);
    l_q += __shfl_xor(l_q, 32);

    // merge jh halves
    __syncthreads();
    if (jh == 1) {
#pragma unroll
        for (int f = 0; f < 8; ++f)
#pragma unroll
            for (int rg = 0; rg < 4; ++rg)
                u.mg.o[r][(f * 16 + quad * 4 + rg) * 17 + l16] = acc[f][rg];
        if (quad == 0) {
            u.mg.m[r][l16] = m_q;
            u.mg.l[r][l16] = l_q;
        }
    }
    __syncthreads();
    if (jh == 0) {
        float m1 = u.mg.m[r][l16], l1 = u.mg.l[r][l16];
        float ms = fmaxf(m_q, m1);
        float a0 = exp2f((m_q - ms) * LOG2E);
        float a1 = exp2f((m1 - ms) * LOG2E);
        float ls = l_q * a0 + l1 * a1;
        float inv = 1.f / ls;
#pragma unroll
        for (int f = 0; f < 8; ++f) {
            half4v hv;
#pragma unroll
            for (int rg = 0; rg < 4; ++rg) {
                float o1 = u.mg.o[r][(f * 16 + quad * 4 + rg) * 17 + l16];
                hv[rg] = (f16)((acc[f][rg] * a0 + o1 * a1) * inv);
            }
            // part_o [bx][query r*16+l16][c]
            *(half4v*)(part_o + (size_t)bx * 4096 + (r * 16 + l16) * 128 + f * 16 + quad * 4) = hv;
        }
        if (quad == 0) {
            part_ml[(size_t)bx * 64 + r * 16 + l16]      = ms;
            part_ml[(size_t)bx * 64 + 32 + r * 16 + l16] = ls;
        }
    }
}

// ---------------------------------------------------------------------------
// K3: fused combine + out-projection + residual.
// h = sum_s w_s part_o_s  (combined during LDS staging), x_t = Wo@h + bo + val.
// grid = B*64 = 128 blocks of 256.
// ---------------------------------------------------------------------------
__global__ __launch_bounds__(256) void k_oproj(
    const f16* __restrict__ part_o, const float* __restrict__ part_ml,
    const void* __restrict__ wo, const void* __restrict__ bo,
    const f16* __restrict__ val_t, float* __restrict__ x_t)
{
    __shared__ f16 wo_lds[128 * 136];
    __shared__ f16 h_lds[64 * 136];
    __shared__ float w4s[2][4][32];   // [it-group][split][row32]

    int bx = blockIdx.x;
    int b = bx >> 6;
    int n0 = (bx & 63) * 64;
    int tid = threadIdx.x;
    int fp32 = sniff_fp32(wo, tid);

    if (tid < 64) {
        int ig = tid >> 5, row = tid & 31;
        size_t base4 = ((size_t)(b * 128 + (n0 >> 5) + ig)) * 4;
        float m[4], l[4];
#pragma unroll
        for (int s = 0; s < 4; ++s) {
            m[s] = part_ml[(base4 + s) * 64 + row];
            l[s] = part_ml[(base4 + s) * 64 + 32 + row];
        }
        float M = fmaxf(fmaxf(m[0], m[1]), fmaxf(m[2], m[3]));
        float sw = 0.f, wv_[4];
#pragma unroll
        for (int s = 0; s < 4; ++s) { wv_[s] = l[s] * exp2f((m[s] - M) * LOG2E); sw += wv_[s]; }
        float inv = 1.f / sw;
#pragma unroll
        for (int s = 0; s < 4; ++s) w4s[ig][s][row] = wv_[s] * inv;
    }
    for (int id = tid; id < 2048; id += 256) {
        int row = id >> 4, c8 = id & 15;
        *(half8*)(wo_lds + row * 136 + c8 * 8) = load8(wo, (size_t)row * 128 + c8 * 8, fp32);
    }
    __syncthreads();

    // stage h = combined partials
    for (int id = tid; id < 1024; id += 256) {
        int row = id >> 4, c8 = id & 15;
        int ig = row >> 5, r32 = row & 31;
        size_t base4 = ((size_t)(b * 128 + (n0 >> 5) + ig)) * 4;
        float o[8] = {};
#pragma unroll
        for (int s = 0; s < 4; ++s) {
            half8 pp = *(const half8*)(part_o + (base4 + s) * 4096 + r32 * 128 + c8 * 8);
            float ws = w4s[ig][s][r32];
#pragma unroll
            for (int k = 0; k < 8; ++k) o[k] += ws * (float)pp[k];
        }
        half8 hh;
#pragma unroll
        for (int k = 0; k < 8; ++k) hh[k] = (f16)o[k];
        *(half8*)(h_lds + row * 136 + c8 * 8) = hh;
    }
    __syncthreads();

    int lane = tid & 63, w = tid >> 6, l16 = lane & 15, quad = lane >> 4;
    floatx4 acc[8] = {};
    for (int kc = 0; kc < 4; ++kc) {
        half8 a = *(half8*)(h_lds + (w * 16 + l16) * 136 + kc * 32 + quad * 8);
#pragma unroll
        for (int f = 0; f < 8; ++f) {
            half8 bf = *(half8*)(wo_lds + (f * 16 + l16) * 136 + kc * 32 + quad * 8);
            acc[f] = __builtin_amdgcn_mfma_f32_16x16x32_f16(a, bf, acc[f], 0, 0, 0);
        }
    }
#pragma unroll
    for (int f = 0; f < 8; ++f) {
        int c = f * 16 + l16;
        float bias = ldf(bo, c, fp32);
#pragma unroll
        for (int rg = 0; rg < 4; ++rg) {
            int n = n0 + w * 16 + quad * 4 + rg;
            size_t off = ((size_t)b * 4096 + n) * 128 + c;
            x_t[off] = acc[f][rg] + bias + (float)val_t[off];
        }
    }
}

// ---------------------------------------------------------------------------
// K4a: group-norm stats (atomicAdd partials).  grid = B*32*4 = 256 blocks.
// ---------------------------------------------------------------------------
__global__ __launch_bounds__(256) void k_gn_stats(
    const float* __restrict__ x_t, float* __restrict__ gacc)
{
    int bx = blockIdx.x;
    int qtr = bx & 3, g = (bx >> 2) & 31, b = bx >> 7;
    int tid = threadIdx.x;

    float s = 0.f, ss = 0.f;
    for (int pass = 0; pass < 4; ++pass) {
        int n = qtr * 1024 + pass * 256 + tid;
        float4 v = *(const float4*)(x_t + ((size_t)b * 4096 + n) * 128 + g * 4);
        s += v.x + v.y + v.z + v.w;
        ss += v.x * v.x + v.y * v.y + v.z * v.z + v.w * v.w;
    }
#pragma unroll
    for (int m = 1; m < 64; m <<= 1) {
        s += __shfl_xor(s, m);
        ss += __shfl_xor(ss, m);
    }
    if ((tid & 63) == 0) {
        atomicAdd(&gacc[(b * 32 + g) * 2], s);
        atomicAdd(&gacc[(b * 32 + g) * 2 + 1], ss);
    }
}

// ---------------------------------------------------------------------------
// K4b: group-norm apply + swish.  grid = B*32*4 = 256 blocks.
// ---------------------------------------------------------------------------
__global__ __launch_bounds__(256) void k_gn_apply(
    const float* __restrict__ x_t, const float* __restrict__ gacc,
    const void* __restrict__ gamma, const void* __restrict__ beta,
    const void* __restrict__ wq_probe, void* __restrict__ out)
{
    int bx = blockIdx.x;
    int qtr = bx & 3, g = (bx >> 2) & 31, b = bx >> 7;
    int tid = threadIdx.x;
    int fp32 = sniff_fp32(wq_probe, tid);

    float S = gacc[(b * 32 + g) * 2], SS = gacc[(b * 32 + g) * 2 + 1];
    float mu = S * (1.f / 16384.f);
    float inv = rsqrtf(SS * (1.f / 16384.f) - mu * mu + 1e-5f);
    float ga[4], be[4];
#pragma unroll
    for (int cc = 0; cc < 4; ++cc) {
        ga[cc] = ldf(gamma, g * 4 + cc, fp32);
        be[cc] = ldf(beta, g * 4 + cc, fp32);
    }

    for (int pass = 0; pass < 4; ++pass) {
        int n = qtr * 1024 + pass * 256 + tid;
        float4 v = *(const float4*)(x_t + ((size_t)b * 4096 + n) * 128 + g * 4);
        float xv[4] = {v.x, v.y, v.z, v.w};
#pragma unroll
        for (int cc = 0; cc < 4; ++cc) {
            float y = (xv[cc] - mu) * inv * ga[cc] + be[cc];
            float sig = 1.f / (1.f + exp2f(-y * LOG2E));
            float res = y * sig;
            size_t o = ((size_t)(b * 128 + g * 4 + cc)) * 4096 + n;
            if (fp32) ((float*)out)[o] = res;
            else      ((__hip_bfloat16*)out)[o] = __float2bfloat16(res);
        }
    }
}

// ---------------------------------------------------------------------------
extern "C" void kernel_launch(void* const* d_in, const int* in_sizes, int n_in,
                              void* d_out, int out_size, void* d_ws, size_t ws_size,
                              hipStream_t stream)
{
    const void* q_in  = d_in[0];
    const void* k_in  = d_in[1];
    const void* v_in  = d_in[2];
    const void* wq    = d_in[3];
    const void* bq    = d_in[4];
    const void* wk    = d_in[5];
    const void* bk    = d_in[6];
    const void* wv    = d_in[7];
    const void* bv    = d_in[8];
    const void* wo    = d_in[9];
    const void* bo    = d_in[10];
    const void* gamma = d_in[11];
    const void* beta  = d_in[12];

    char* ws = (char*)d_ws;
    f16*   q_t     = (f16*)(ws);                       // 0..2 MB   [B][N][C]
    f16*   k_t     = (f16*)(ws + (2u << 20));          // 2..4 MB   [B][N][C]
    f16*   v_n     = (f16*)(ws + (4u << 20));          // 4..6 MB   [B][C][N]
    f16*   val_t   = (f16*)(ws + (6u << 20));          // 6..8 MB   [B][N][C]
    f16*   part_o  = (f16*)(ws + (10u << 20));         // 10..18 MB [1024][32][128]
    float* part_ml = (float*)(ws + (18u << 20));       // 18..18.25 MB
    float* gacc    = (float*)(ws + (18u << 20) + (512u << 10)); // 512 B @ 18.5 MB
    float* x_t     = (float*)(ws);                     // 0..4 MB (q_t/k_t dead by then)

    hipMemsetAsync(gacc, 0, 2 * 32 * 2 * sizeof(float), stream);
    k_qkv<<<384, 256, 0, stream>>>(q_in, k_in, v_in, wq, bq, wk, bk, wv, bv,
                                   q_t, k_t, v_n, val_t);
    k_attn<<<1024, 256, 0, stream>>>(q_t, k_t, v_n, part_o, part_ml);
    k_oproj<<<128, 256, 0, stream>>>(part_o, part_ml, wo, bo, val_t, x_t);
    k_gn_stats<<<256, 256, 0, stream>>>(x_t, gacc);
    k_gn_apply<<<256, 256, 0, stream>>>(x_t, gacc, gamma, beta, wq, d_out);
}